// Round 7
// baseline (1966.551 us; speedup 1.0000x reference)
//
#include <hip/hip_runtime.h>
#include <hip/hip_bf16.h>

typedef _Float16 half8 __attribute__((ext_vector_type(8)));
typedef float floatx4 __attribute__((ext_vector_type(4)));
typedef float floatx2 __attribute__((ext_vector_type(2)));

#define N_NODES 10000
#define F_NODE  128
#define C_GCN   64
#define N_EDGES 160000
#define T_SEQ   96
#define S_SEQ   32
#define HID     128
#define M_BLK   40          // nodes per block (250 blocks exactly)
#define MT      3           // 3 m-tiles of 16 -> 48 rows (40 real + 8 zero pad)
#define SEQ_STRIDE 104      // 96 + 8 f16 pad
#define H_STRIDE   136      // 128 + 8 f16 pad
// pP layout: resident region [wave:8][entry:24][lane:64]x16B = 196,608 B
//            streamed region [wave:8][slot:9][gate:4][lane:64]x16B = 294,912 B
#define RES_SZ    196608
#define RES_WAVE  24576
#define STR_WAVE  36864

// ---------------- fast activations ----------------
__device__ __forceinline__ float fast_rcp(float x) { return __builtin_amdgcn_rcpf(x); }
__device__ __forceinline__ float sigm_f(float x) {
    return fast_rcp(1.0f + __expf(-x));
}
__device__ __forceinline__ float tanh_f(float x) {
    return 2.0f * fast_rcp(1.0f + __expf(-2.0f * x)) - 1.0f;
}

// ---------------- GCN kernels (unchanged) ----------------
__global__ void k_gcn_xw(const float* __restrict__ nf, const float* __restrict__ w,
                         float* __restrict__ xw) {
    int tid = blockIdx.x * 256 + threadIdx.x;
    int n = tid >> 6, c = tid & 63;
    if (n >= N_NODES) return;
    float s = 0.f;
    #pragma unroll 8
    for (int k = 0; k < F_NODE; ++k) s = fmaf(nf[n * F_NODE + k], w[k * C_GCN + c], s);
    xw[n * C_GCN + c] = s;
}

__global__ void k_deg_init(float* __restrict__ deg) {
    int i = blockIdx.x * 256 + threadIdx.x;
    if (i < N_NODES) deg[i] = 1.0f;
}

__global__ void k_deg_count(const int* __restrict__ ei, float* __restrict__ deg) {
    int e = blockIdx.x * 256 + threadIdx.x;
    if (e < N_EDGES) atomicAdd(&deg[ei[N_EDGES + e]], 1.0f);
}

__global__ void k_dinv(const float* __restrict__ deg, float* __restrict__ dinv) {
    int i = blockIdx.x * 256 + threadIdx.x;
    if (i < N_NODES) dinv[i] = rsqrtf(deg[i]);
}

__global__ void k_gcn_self(const float* __restrict__ xw, const float* __restrict__ dinv,
                           const float* __restrict__ gb, float* __restrict__ gout) {
    int tid = blockIdx.x * 256 + threadIdx.x;
    int n = tid >> 6, c = tid & 63;
    if (n >= N_NODES) return;
    float di = dinv[n];
    gout[tid] = xw[tid] * di * di + gb[c];
}

__global__ void k_gcn_scatter(const int* __restrict__ ei, const float* __restrict__ xw,
                              const float* __restrict__ dinv, float* __restrict__ gout) {
    int e = blockIdx.x * 4 + (threadIdx.x >> 6);
    int c = threadIdx.x & 63;
    if (e >= N_EDGES) return;
    int r  = ei[e];
    int cl = ei[N_EDGES + e];
    float nm = dinv[r] * dinv[cl];
    atomicAdd(&gout[cl * C_GCN + c], xw[r * C_GCN + c] * nm);
}

// ---------------- weight packing ----------------
// Resident (per wave): entries e=0..23: i=e>>2 (0..2 IH0 kt0..2, 3..5 HH0 kt0..2), g=e&3.
// Streamed (per wave): 9 slots: s0=HH0 kt3, s1..4=IH1 kt0..3, s5..8=HH1 kt0..3.
// lane holds W[g*128 + w*16 + (lane&15)][kt*32 + (lane>>4)*8 + j]
__global__ void k_pack(const float* __restrict__ w_ih0, const float* __restrict__ w_hh0,
                       const float* __restrict__ w_ih1, const float* __restrict__ w_hh1,
                       char* __restrict__ pP) {
    int tid = blockIdx.x * 256 + threadIdx.x;
    if (tid >= 30720) return;
    int lane = tid & 63;
    int rest = tid >> 6;          // 0..479
    int w    = rest / 60;
    int idx  = rest % 60;
    const float* src; int K, kt, g;
    size_t dst;
    if (idx < 24) {               // resident
        int i = idx >> 2; g = idx & 3;
        int grp = i / 3; kt = i % 3;
        src = grp ? w_hh0 : w_ih0; K = grp ? 128 : 96;
        dst = (size_t)w * RES_WAVE + (size_t)idx * 1024 + lane * 16;
    } else {                      // streamed
        int j = idx - 24; int s = j >> 2; g = j & 3;
        if (s == 0)      { src = w_hh0; kt = 3; }
        else if (s <= 4) { src = w_ih1; kt = s - 1; }
        else             { src = w_hh1; kt = s - 5; }
        K = 128;
        dst = (size_t)RES_SZ + (size_t)w * STR_WAVE + (size_t)s * 4096 + (size_t)g * 1024 + lane * 16;
    }
    int row = g * 128 + w * 16 + (lane & 15);
    int k0  = kt * 32 + (lane >> 4) * 8;
    half8 v;
    #pragma unroll
    for (int j = 0; j < 8; ++j) v[j] = (_Float16)src[row * K + k0 + j];
    *(half8*)(pP + dst) = v;
}

__global__ void k_bsum(const float* __restrict__ bi0, const float* __restrict__ bh0,
                       const float* __restrict__ bi1, const float* __restrict__ bh1,
                       float* __restrict__ bs) {
    int i = blockIdx.x * 256 + threadIdx.x;
    if (i < 512)       bs[i] = bi0[i] + bh0[i];
    else if (i < 1024) bs[i] = bi1[i - 512] + bh1[i - 512];
}

// ---------------- fused 2-layer LSTM + FC ----------------
// IH0+HH0 kt0..2 live in REGISTERS (96 VGPR, loaded once) -> phase A is 6
// register-direct MFMA tiles + 1 streamed slot. Only 9 slots/step stream
// through LDS (9%3==0 -> ring map step-invariant). Counted vmcnt throughout;
// queue never drains in-loop. Waves 4-7 rotated (round-6 win, kept).

__device__ __forceinline__ void async_copy16(const void* g, void* l) {
    __builtin_amdgcn_global_load_lds(
        (const __attribute__((address_space(1))) unsigned int*)g,
        (__attribute__((address_space(3))) unsigned int*)l, 16, 0, 0);
}

__device__ __forceinline__ void dma_slot(const char* __restrict__ src, int lane, _Float16* slot) {
    #pragma unroll
    for (int g = 0; g < 4; ++g)
        async_copy16((const void*)(src + g * 1024 + lane * 16), (void*)(slot + g * 512));
}

#define VMW(N) asm volatile("s_waitcnt vmcnt(" #N ")" ::: "memory")

#define BARRIER_NOVM() do {                                   \
    asm volatile("s_waitcnt lgkmcnt(0)" ::: "memory");        \
    __builtin_amdgcn_s_barrier();                             \
    asm volatile("" ::: "memory");                            \
} while (0)

#define RDB(BG, BUF) {                                                      \
    _Pragma("unroll")                                                       \
    for (int g = 0; g < 4; ++g) (BG)[g] = *(const half8*)((BUF) + g * 512 + lane * 8); }

#define RDA(AA, APTR, KOFF, ASTR) {                                         \
    _Pragma("unroll")                                                       \
    for (int mt = 0; mt < MT; ++mt)                                         \
        (AA)[mt] = *(const half8*)((APTR) + (mt * 16 + l15) * (ASTR) + (KOFF) + quad * 8); }

#define MM(AA, BG) {                                                        \
    _Pragma("unroll")                                                       \
    for (int g = 0; g < 4; ++g)                                             \
        _Pragma("unroll")                                                   \
        for (int mt = 0; mt < MT; ++mt)                                     \
            acc[g][mt] = __builtin_amdgcn_mfma_f32_16x16x32_f16((AA)[mt], (BG)[g], acc[g][mt], 0, 0, 0); }

#define ACCINIT(B) {                                                        \
    _Pragma("unroll")                                                       \
    for (int g = 0; g < 4; ++g) {                                           \
        floatx4 bv = {(B)[g], (B)[g], (B)[g], (B)[g]};                      \
        _Pragma("unroll")                                                   \
        for (int mt = 0; mt < MT; ++mt) acc[g][mt] = bv;                    \
    } }

__device__ __forceinline__ void epilogue(floatx4 acc[4][MT],
                                         float c[MT][4], _Float16* Hnext,
                                         int quad, int ch) {
    #pragma unroll
    for (int mt = 0; mt < MT; ++mt) {
        #pragma unroll
        for (int r = 0; r < 4; ++r) {
            float gi = acc[0][mt][r];
            float gf = acc[1][mt][r];
            float gg = acc[2][mt][r];
            float go = acc[3][mt][r];
            float cn = sigm_f(gf) * c[mt][r] + sigm_f(gi) * tanh_f(gg);
            c[mt][r] = cn;
            float h = sigm_f(go) * tanh_f(cn);
            Hnext[(mt * 16 + quad * 4 + r) * H_STRIDE + ch] = (_Float16)h;
        }
    }
}

__global__ __launch_bounds__(512, 2) void k_lstm(
    const float* __restrict__ seq, const float* __restrict__ gcn,
    const char* __restrict__ pW, const float* __restrict__ bsum,
    const float* __restrict__ fcw, const float* __restrict__ fcb,
    float* __restrict__ out) {

    __shared__ __align__(16) _Float16 sSeq[48 * SEQ_STRIDE];          //  9,984 B
    __shared__ __align__(16) _Float16 sH0[2][48 * H_STRIDE];          // 26,112 B
    __shared__ __align__(16) _Float16 sH1[2][48 * H_STRIDE];          // 26,112 B
    __shared__ __align__(16) _Float16 sWa[8][2048];                   // 32,768 B
    __shared__ __align__(16) _Float16 sWb[8][2048];                   // 32,768 B
    __shared__ __align__(16) _Float16 sWc[8][2048];                   // 32,768 B

    const int tid  = threadIdx.x;
    const int wid  = tid >> 6;
    const int lane = tid & 63;
    const int l15  = lane & 15;
    const int quad = lane >> 4;
    const int node0 = blockIdx.x * M_BLK;
    const int ch = wid * 16 + l15;
    const bool rot = (wid >= 4);

    _Float16* const rb0 = &sWa[wid][0];
    _Float16* const rb1 = &sWb[wid][0];
    _Float16* const rb2 = &sWc[wid][0];

    const char* pSw = pW + RES_SZ + (size_t)wid * STR_WAVE;   // streamed slots

#define DMA(S, RB) dma_slot(pSw + (S) * 4096, lane, (RB))

    // resident weights: IH0 kt0..2 (rW[0..2]), HH0 kt0..2 (rW[3..5]) -- 96 VGPR
    half8 rW[6][4];
    {
        const half8* pR = (const half8*)(pW + (size_t)wid * RES_WAVE);
        #pragma unroll
        for (int i = 0; i < 6; ++i)
            #pragma unroll
            for (int g = 0; g < 4; ++g)
                rW[i][g] = pR[(i * 4 + g) * 64 + lane];
    }

    // zero LDS A-buffers (pad rows 40..47 stay zero forever)
    for (int i = tid; i < 48 * SEQ_STRIDE; i += 512) sSeq[i] = (_Float16)0.f;
    for (int i = tid; i < 48 * H_STRIDE; i += 512) {
        sH0[0][i] = (_Float16)0.f; sH0[1][i] = (_Float16)0.f;
        sH1[0][i] = (_Float16)0.f; sH1[1][i] = (_Float16)0.f;
    }

    float bias0[4], bias1[4];
    #pragma unroll
    for (int g = 0; g < 4; ++g) {
        bias0[g] = bsum[g * 128 + ch];
        bias1[g] = bsum[512 + g * 128 + ch];
    }

    float c0[MT][4] = {{0}}, c1[MT][4] = {{0}};

    __syncthreads();

    // stage constant gcn columns (32..95) and seq t=0 (cols 0..31)
    for (int i = tid; i < M_BLK * (C_GCN / 2); i += 512) {
        int r = i >> 5, cp = (i & 31) * 2;
        floatx2 v = *(const floatx2*)(gcn + (size_t)(node0 + r) * C_GCN + cp);
        sSeq[r * SEQ_STRIDE + S_SEQ + cp]     = (_Float16)v.x;
        sSeq[r * SEQ_STRIDE + S_SEQ + cp + 1] = (_Float16)v.y;
    }
    {
        int r = tid >> 4, cp = (tid & 15) * 2;
        if (tid < M_BLK * 16) {
            floatx2 v = *(const floatx2*)(seq + ((size_t)(node0 + r) * T_SEQ) * S_SEQ + cp);
            sSeq[r * SEQ_STRIDE + cp]     = (_Float16)v.x;
            sSeq[r * SEQ_STRIDE + cp + 1] = (_Float16)v.y;
        }
    }
    __syncthreads();   // full drain: loop starts from an empty vm queue

    // prologue DMA: first 3 streamed slots of THIS WAVE'S consume order
    if (!rot) { DMA(0, rb0); DMA(1, rb1); DMA(2, rb2); }
    else      { DMA(0, rb0); DMA(5, rb1); DMA(6, rb2); }

    floatx4 acc[4][MT];
    half8 aX[MT], aY[MT], bX[4], bY[4];

    const int pr = tid >> 4, pc = (tid & 15) * 2;
    const int r1 = 32 + ((tid & 127) >> 4);
    floatx2 pfa, pfb;

    if (!rot) {
      // ================== canonical order (waves 0-3) ==================
      for (int t = 0; t < T_SEQ; ++t) {
        const int cur = t & 1, nxt = cur ^ 1;
        const _Float16* h0c = &sH0[cur][0];
        _Float16*       h0n = &sH0[nxt][0];
        const _Float16* h1c = &sH1[cur][0];
        _Float16*       h1n = &sH1[nxt][0];
        {
            int tp = (t + 1 < T_SEQ) ? (t + 1) : (T_SEQ - 1);
            pfa = *(const floatx2*)(seq + ((size_t)(node0 + pr) * T_SEQ + tp) * S_SEQ + pc);
            pfb = *(const floatx2*)(seq + ((size_t)(node0 + r1) * T_SEQ + tp) * S_SEQ + pc);
        }
        // ---- phase A: IH0 kt0..2 (resident), HH0 kt0..2 (resident), s0 ----
        ACCINIT(bias0);
        RDA(aX, sSeq, 0, SEQ_STRIDE);
        RDA(aY, sSeq, 32, SEQ_STRIDE);   MM(aX, rW[0]);
        RDA(aX, sSeq, 64, SEQ_STRIDE);   MM(aY, rW[1]);
        RDA(aY, h0c, 0,  H_STRIDE);      MM(aX, rW[2]);
        RDA(aX, h0c, 32, H_STRIDE);      MM(aY, rW[3]);
        RDA(aY, h0c, 64, H_STRIDE);      MM(aX, rW[4]);
        VMW(8); RDB(bX, rb0);            // s0 landed (3 slots + pf in queue)
        RDA(aX, h0c, 96, H_STRIDE);      MM(aY, rW[5]);
        MM(aX, bX);                      // s0 = HH0 kt3
        epilogue(acc, c0, h0n, quad, ch);
        BARRIER_NOVM();
        // ---- phase B: s1..s4 (IH1 x h0n), s5..s8 (HH1 x h1c) ----
        ACCINIT(bias1);
        VMW(4); RDB(bY, rb1); RDA(aY, h0n, 0, H_STRIDE); DMA(3, rb0);
        VMW(4); RDB(bX, rb2); RDA(aX, h0n, 32, H_STRIDE); MM(aY, bY); DMA(4, rb1);  // s1
        VMW(4); RDB(bY, rb0); RDA(aY, h0n, 64, H_STRIDE); MM(aX, bX); DMA(5, rb2);  // s2
        VMW(4); RDB(bX, rb1); RDA(aX, h0n, 96, H_STRIDE); MM(aY, bY); DMA(6, rb0);  // s3
        VMW(4); RDB(bY, rb2); RDA(aY, h1c, 0,  H_STRIDE); MM(aX, bX); DMA(7, rb1);  // s4
        VMW(4); RDB(bX, rb0); RDA(aX, h1c, 32, H_STRIDE); MM(aY, bY); DMA(8, rb2);  // s5
        VMW(4); RDB(bY, rb1); RDA(aY, h1c, 64, H_STRIDE); MM(aX, bX); DMA(0, rb0);  // s6 (+s0')
        VMW(4); RDB(bX, rb2); RDA(aX, h1c, 96, H_STRIDE); MM(aY, bY); DMA(1, rb1);  // s7 (+s1')
        MM(aX, bX); DMA(2, rb2);                                                     // s8 (+s2')
        if (t + 1 < T_SEQ) {
            sSeq[pr * SEQ_STRIDE + pc]     = (_Float16)pfa.x;
            sSeq[pr * SEQ_STRIDE + pc + 1] = (_Float16)pfa.y;
            if (tid < 128) {
                sSeq[r1 * SEQ_STRIDE + pc]     = (_Float16)pfb.x;
                sSeq[r1 * SEQ_STRIDE + pc + 1] = (_Float16)pfb.y;
            }
        }
        epilogue(acc, c1, h1n, quad, ch);
        BARRIER_NOVM();
      }
    } else {
      // ================== rotated order (waves 4-7) ==================
      // phase A: HH0 kt0..2, s0, IH0 kt0..2.  phase B: s5..s8 then s1..s4.
      for (int t = 0; t < T_SEQ; ++t) {
        const int cur = t & 1, nxt = cur ^ 1;
        const _Float16* h0c = &sH0[cur][0];
        _Float16*       h0n = &sH0[nxt][0];
        const _Float16* h1c = &sH1[cur][0];
        _Float16*       h1n = &sH1[nxt][0];
        {
            int tp = (t + 1 < T_SEQ) ? (t + 1) : (T_SEQ - 1);
            pfa = *(const floatx2*)(seq + ((size_t)(node0 + pr) * T_SEQ + tp) * S_SEQ + pc);
            pfb = *(const floatx2*)(seq + ((size_t)(node0 + r1) * T_SEQ + tp) * S_SEQ + pc);
        }
        // ---- phase A rotated ----
        ACCINIT(bias0);
        RDA(aX, h0c, 0, H_STRIDE);
        RDA(aY, h0c, 32, H_STRIDE);      MM(aX, rW[3]);
        RDA(aX, h0c, 64, H_STRIDE);      MM(aY, rW[4]);
        VMW(8); RDB(bX, rb0);
        RDA(aY, h0c, 96, H_STRIDE);      MM(aX, rW[5]);
        RDA(aX, sSeq, 0, SEQ_STRIDE);    MM(aY, bX);      // s0 = HH0 kt3
        RDA(aY, sSeq, 32, SEQ_STRIDE);   MM(aX, rW[0]);
        RDA(aX, sSeq, 64, SEQ_STRIDE);   MM(aY, rW[1]);
        MM(aX, rW[2]);
        epilogue(acc, c0, h0n, quad, ch);
        BARRIER_NOVM();
        // ---- phase B rotated: s5..s8 (HH1 x h1c), s1..s4 (IH1 x h0n) ----
        ACCINIT(bias1);
        VMW(4); RDB(bY, rb1); RDA(aY, h1c, 0, H_STRIDE); DMA(7, rb0);
        VMW(4); RDB(bX, rb2); RDA(aX, h1c, 32, H_STRIDE); MM(aY, bY); DMA(8, rb1);  // s5
        VMW(4); RDB(bY, rb0); RDA(aY, h1c, 64, H_STRIDE); MM(aX, bX); DMA(1, rb2);  // s6
        VMW(4); RDB(bX, rb1); RDA(aX, h1c, 96, H_STRIDE); MM(aY, bY); DMA(2, rb0);  // s7
        VMW(4); RDB(bY, rb2); RDA(aY, h0n, 0,  H_STRIDE); MM(aX, bX); DMA(3, rb1);  // s8
        VMW(4); RDB(bX, rb0); RDA(aX, h0n, 32, H_STRIDE); MM(aY, bY); DMA(4, rb2);  // s1
        VMW(4); RDB(bY, rb1); RDA(aY, h0n, 64, H_STRIDE); MM(aX, bX); DMA(0, rb0);  // s2 (+s0')
        VMW(4); RDB(bX, rb2); RDA(aX, h0n, 96, H_STRIDE); MM(aY, bY); DMA(5, rb1);  // s3 (+s5')
        MM(aX, bX); DMA(6, rb2);                                                     // s4 (+s6')
        if (t + 1 < T_SEQ) {
            sSeq[pr * SEQ_STRIDE + pc]     = (_Float16)pfa.x;
            sSeq[pr * SEQ_STRIDE + pc + 1] = (_Float16)pfa.y;
            if (tid < 128) {
                sSeq[r1 * SEQ_STRIDE + pc]     = (_Float16)pfb.x;
                sSeq[r1 * SEQ_STRIDE + pc + 1] = (_Float16)pfb.y;
            }
        }
        epilogue(acc, c1, h1n, quad, ch);
        BARRIER_NOVM();
      }
    }

#undef DMA

    // drain the 3 slots prefetched for the nonexistent step 96
    asm volatile("s_waitcnt vmcnt(0)" ::: "memory");

    // final h1 lives in buffer (T_SEQ & 1) == 0
    if (tid < M_BLK) {
        const _Float16* h1 = &sH1[0][tid * H_STRIDE];
        float s = fcb[0];
        #pragma unroll 16
        for (int k = 0; k < HID; ++k) s = fmaf((float)h1[k], fcw[k], s);
        out[node0 + tid] = s;
    }
}

// ---------------- launch ----------------
extern "C" void kernel_launch(void* const* d_in, const int* in_sizes, int n_in,
                              void* d_out, int out_size, void* d_ws, size_t ws_size,
                              hipStream_t stream) {
    const float* seq   = (const float*)d_in[0];
    const int*   ei    = (const int*)d_in[1];
    const float* nf    = (const float*)d_in[3];
    const float* gcn_w = (const float*)d_in[5];
    const float* gcn_b = (const float*)d_in[6];
    const float* w_ih0 = (const float*)d_in[7];
    const float* w_hh0 = (const float*)d_in[8];
    const float* b_ih0 = (const float*)d_in[9];
    const float* b_hh0 = (const float*)d_in[10];
    const float* w_ih1 = (const float*)d_in[11];
    const float* w_hh1 = (const float*)d_in[12];
    const float* b_ih1 = (const float*)d_in[13];
    const float* b_hh1 = (const float*)d_in[14];
    const float* fc_w  = (const float*)d_in[15];
    const float* fc_b  = (const float*)d_in[16];
    float* out = (float*)d_out;

    char* ws = (char*)d_ws;
    float* xw   = (float*)(ws);                    // 2,560,000 B
    float* gout = (float*)(ws + 2621440);          // 2,560,000 B
    float* deg  = (float*)(ws + 5242880);          // 40,000 B
    float* dinv = (float*)(ws + 5283840);          // 40,000 B
    float* bsum = (float*)(ws + 5324800);          // 4,096 B
    char*  pP   = (char*)(ws + 5328896);           // 491,520 B

    // GCN (fp32 exact)
    k_gcn_xw     <<<2500,  256, 0, stream>>>(nf, gcn_w, xw);
    k_deg_init   <<<40,    256, 0, stream>>>(deg);
    k_deg_count  <<<625,   256, 0, stream>>>(ei, deg);
    k_dinv       <<<40,    256, 0, stream>>>(deg, dinv);
    k_gcn_self   <<<2500,  256, 0, stream>>>(xw, dinv, gcn_b, gout);
    k_gcn_scatter<<<40000, 256, 0, stream>>>(ei, xw, dinv, gout);

    // weight prep (resident + streamed layout)
    k_pack<<<120, 256, 0, stream>>>(w_ih0, w_hh0, w_ih1, w_hh1, pP);
    k_bsum<<<4,   256, 0, stream>>>(b_ih0, b_hh0, b_ih1, b_hh1, bsum);

    // fused 2-layer LSTM + FC
    k_lstm<<<250, 512, 0, stream>>>(seq, gout, pP, bsum, fc_w, fc_b, out);
}

// Round 8
// 1900.615 us; speedup vs baseline: 1.0347x; 1.0347x over previous
//
#include <hip/hip_runtime.h>
#include <hip/hip_bf16.h>

typedef _Float16 half8 __attribute__((ext_vector_type(8)));
typedef float floatx4 __attribute__((ext_vector_type(4)));
typedef float floatx2 __attribute__((ext_vector_type(2)));

#define N_NODES 10000
#define F_NODE  128
#define C_GCN   64
#define N_EDGES 160000
#define T_SEQ   96
#define S_SEQ   32
#define HID     128
#define M_BLK   40          // nodes per block (250 blocks exactly)
#define MT      3           // 3 m-tiles of 16 -> 48 rows (40 real + 8 zero pad)
#define SEQ_STRIDE 104      // 96 + 8 f16 pad
#define H_STRIDE   136      // 128 + 8 f16 pad
// pP layout: resident region [wave:8][entry:12][lane:64]x16B = 98,304 B (IH0 kt0..2)
//            streamed region [wave:8][slot:12][gate:4][lane:64]x16B = 393,216 B
//            slots: s0..3 = HH0 kt0..3, s4..7 = IH1 kt0..3, s8..11 = HH1 kt0..3
#define RES_WAVE  12288
#define RES_SZ    98304
#define STR_WAVE  49152

// ---------------- fast activations ----------------
__device__ __forceinline__ float fast_rcp(float x) { return __builtin_amdgcn_rcpf(x); }
__device__ __forceinline__ float sigm_f(float x) {
    return fast_rcp(1.0f + __expf(-x));
}
__device__ __forceinline__ float tanh_f(float x) {
    return 2.0f * fast_rcp(1.0f + __expf(-2.0f * x)) - 1.0f;
}

// ---------------- GCN kernels (unchanged) ----------------
__global__ void k_gcn_xw(const float* __restrict__ nf, const float* __restrict__ w,
                         float* __restrict__ xw) {
    int tid = blockIdx.x * 256 + threadIdx.x;
    int n = tid >> 6, c = tid & 63;
    if (n >= N_NODES) return;
    float s = 0.f;
    #pragma unroll 8
    for (int k = 0; k < F_NODE; ++k) s = fmaf(nf[n * F_NODE + k], w[k * C_GCN + c], s);
    xw[n * C_GCN + c] = s;
}

__global__ void k_deg_init(float* __restrict__ deg) {
    int i = blockIdx.x * 256 + threadIdx.x;
    if (i < N_NODES) deg[i] = 1.0f;
}

__global__ void k_deg_count(const int* __restrict__ ei, float* __restrict__ deg) {
    int e = blockIdx.x * 256 + threadIdx.x;
    if (e < N_EDGES) atomicAdd(&deg[ei[N_EDGES + e]], 1.0f);
}

__global__ void k_dinv(const float* __restrict__ deg, float* __restrict__ dinv) {
    int i = blockIdx.x * 256 + threadIdx.x;
    if (i < N_NODES) dinv[i] = rsqrtf(deg[i]);
}

__global__ void k_gcn_self(const float* __restrict__ xw, const float* __restrict__ dinv,
                           const float* __restrict__ gb, float* __restrict__ gout) {
    int tid = blockIdx.x * 256 + threadIdx.x;
    int n = tid >> 6, c = tid & 63;
    if (n >= N_NODES) return;
    float di = dinv[n];
    gout[tid] = xw[tid] * di * di + gb[c];
}

__global__ void k_gcn_scatter(const int* __restrict__ ei, const float* __restrict__ xw,
                              const float* __restrict__ dinv, float* __restrict__ gout) {
    int e = blockIdx.x * 4 + (threadIdx.x >> 6);
    int c = threadIdx.x & 63;
    if (e >= N_EDGES) return;
    int r  = ei[e];
    int cl = ei[N_EDGES + e];
    float nm = dinv[r] * dinv[cl];
    atomicAdd(&gout[cl * C_GCN + c], xw[r * C_GCN + c] * nm);
}

// ---------------- weight packing ----------------
// lane holds W[g*128 + w*16 + (lane&15)][kt*32 + (lane>>4)*8 + j]
__global__ void k_pack(const float* __restrict__ w_ih0, const float* __restrict__ w_hh0,
                       const float* __restrict__ w_ih1, const float* __restrict__ w_hh1,
                       char* __restrict__ pP) {
    int tid = blockIdx.x * 256 + threadIdx.x;
    if (tid >= 30720) return;
    int lane = tid & 63;
    int rest = tid >> 6;          // 0..479
    int w    = rest / 60;
    int idx  = rest % 60;
    const float* src; int K, kt, g;
    size_t dst;
    if (idx < 12) {               // resident: IH0 kt0..2
        int i = idx >> 2; g = idx & 3;
        src = w_ih0; K = 96; kt = i;
        dst = (size_t)w * RES_WAVE + (size_t)idx * 1024 + lane * 16;
    } else {                      // streamed: 12 slots
        int j = idx - 12; int s = j >> 2; g = j & 3;
        if (s < 4)      { src = w_hh0; kt = s;     }
        else if (s < 8) { src = w_ih1; kt = s - 4; }
        else            { src = w_hh1; kt = s - 8; }
        K = 128;
        dst = (size_t)RES_SZ + (size_t)w * STR_WAVE + (size_t)s * 4096 + (size_t)g * 1024 + lane * 16;
    }
    int row = g * 128 + w * 16 + (lane & 15);
    int k0  = kt * 32 + (lane >> 4) * 8;
    half8 v;
    #pragma unroll
    for (int j = 0; j < 8; ++j) v[j] = (_Float16)src[row * K + k0 + j];
    *(half8*)(pP + dst) = v;
}

__global__ void k_bsum(const float* __restrict__ bi0, const float* __restrict__ bh0,
                       const float* __restrict__ bi1, const float* __restrict__ bh1,
                       float* __restrict__ bs) {
    int i = blockIdx.x * 256 + threadIdx.x;
    if (i < 512)       bs[i] = bi0[i] + bh0[i];
    else if (i < 1024) bs[i] = bi1[i - 512] + bh1[i - 512];
}

// ---------------- fused 2-layer LSTM + FC ----------------
// IH0 kt0..2 resident in 12 NAMED half8 registers (48 VGPR, loaded once).
// 12 streamed slots via global_load_lds, 3-buffer ring keyed by CONSUME position
// (12%3==0 -> step-invariant). Hand-counted vmcnt (VMW(10)x3 + VMW(8)x8 per
// step; never 0 in-loop). Waves 4-7 rotated (round-6 win).

__device__ __forceinline__ void async_copy16(const void* g, void* l) {
    __builtin_amdgcn_global_load_lds(
        (const __attribute__((address_space(1))) unsigned int*)g,
        (__attribute__((address_space(3))) unsigned int*)l, 16, 0, 0);
}

__device__ __forceinline__ void dma_slot(const char* __restrict__ src, int lane, _Float16* slot) {
    #pragma unroll
    for (int g = 0; g < 4; ++g)
        async_copy16((const void*)(src + g * 1024 + lane * 16), (void*)(slot + g * 512));
}

#define VMW(N) asm volatile("s_waitcnt vmcnt(" #N ")" ::: "memory")

#define BARRIER_NOVM() do {                                   \
    asm volatile("s_waitcnt lgkmcnt(0)" ::: "memory");        \
    __builtin_amdgcn_s_barrier();                             \
    asm volatile("" ::: "memory");                            \
} while (0)

// read 4 B-gate frags of one LDS slot into 4 named regs
#define RDB4(B0, B1, B2, B3, BUF) {                                         \
    B0 = *(const half8*)((BUF) + 0 * 512 + lane * 8);                       \
    B1 = *(const half8*)((BUF) + 1 * 512 + lane * 8);                       \
    B2 = *(const half8*)((BUF) + 2 * 512 + lane * 8);                       \
    B3 = *(const half8*)((BUF) + 3 * 512 + lane * 8); }

// read 3 A frags into a register set
#define RDA(AA, APTR, KOFF, ASTR) {                                         \
    _Pragma("unroll")                                                       \
    for (int mt = 0; mt < MT; ++mt)                                         \
        (AA)[mt] = *(const half8*)((APTR) + (mt * 16 + l15) * (ASTR) + (KOFF) + quad * 8); }

// 12 MFMAs on a loaded A set with 4 named B regs
#define MM4(AA, B0, B1, B2, B3) {                                           \
    _Pragma("unroll")                                                       \
    for (int mt = 0; mt < MT; ++mt) {                                       \
        acc[0][mt] = __builtin_amdgcn_mfma_f32_16x16x32_f16((AA)[mt], B0, acc[0][mt], 0, 0, 0); \
        acc[1][mt] = __builtin_amdgcn_mfma_f32_16x16x32_f16((AA)[mt], B1, acc[1][mt], 0, 0, 0); \
        acc[2][mt] = __builtin_amdgcn_mfma_f32_16x16x32_f16((AA)[mt], B2, acc[2][mt], 0, 0, 0); \
        acc[3][mt] = __builtin_amdgcn_mfma_f32_16x16x32_f16((AA)[mt], B3, acc[3][mt], 0, 0, 0); } }

#define ACCINIT(B) {                                                        \
    _Pragma("unroll")                                                       \
    for (int g = 0; g < 4; ++g) {                                           \
        floatx4 bv = {(B)[g], (B)[g], (B)[g], (B)[g]};                      \
        _Pragma("unroll")                                                   \
        for (int mt = 0; mt < MT; ++mt) acc[g][mt] = bv;                    \
    } }

__device__ __forceinline__ void epilogue(floatx4 acc[4][MT],
                                         float c[MT][4], _Float16* Hnext,
                                         int quad, int ch) {
    #pragma unroll
    for (int mt = 0; mt < MT; ++mt) {
        #pragma unroll
        for (int r = 0; r < 4; ++r) {
            float gi = acc[0][mt][r];
            float gf = acc[1][mt][r];
            float gg = acc[2][mt][r];
            float go = acc[3][mt][r];
            float cn = sigm_f(gf) * c[mt][r] + sigm_f(gi) * tanh_f(gg);
            c[mt][r] = cn;
            float h = sigm_f(go) * tanh_f(cn);
            Hnext[(mt * 16 + quad * 4 + r) * H_STRIDE + ch] = (_Float16)h;
        }
    }
}

__global__ __launch_bounds__(512, 2) void k_lstm(
    const float* __restrict__ seq, const float* __restrict__ gcn,
    const char* __restrict__ pW, const float* __restrict__ bsum,
    const float* __restrict__ fcw, const float* __restrict__ fcb,
    float* __restrict__ out) {

    __shared__ __align__(16) _Float16 sSeq[48 * SEQ_STRIDE];          //  9,984 B
    __shared__ __align__(16) _Float16 sH0[2][48 * H_STRIDE];          // 26,112 B
    __shared__ __align__(16) _Float16 sH1[2][48 * H_STRIDE];          // 26,112 B
    __shared__ __align__(16) _Float16 sWa[8][2048];                   // 32,768 B
    __shared__ __align__(16) _Float16 sWb[8][2048];                   // 32,768 B
    __shared__ __align__(16) _Float16 sWc[8][2048];                   // 32,768 B

    const int tid  = threadIdx.x;
    const int wid  = tid >> 6;
    const int lane = tid & 63;
    const int l15  = lane & 15;
    const int quad = lane >> 4;
    const int node0 = blockIdx.x * M_BLK;
    const int ch = wid * 16 + l15;
    const bool rot = (wid >= 4);

    _Float16* const rb0 = &sWa[wid][0];
    _Float16* const rb1 = &sWb[wid][0];
    _Float16* const rb2 = &sWc[wid][0];

    const char* pSw = pW + RES_SZ + (size_t)wid * STR_WAVE;

#define DMA(S, RB) dma_slot(pSw + (S) * 4096, lane, (RB))

    // prologue DMA: streamed slots 0..2 (same first-3 for both wave orders)
    DMA(0, rb0); DMA(1, rb1); DMA(2, rb2);

    // resident IH0 weights: 12 NAMED half8 (48 VGPR), loaded once
    half8 rw00, rw01, rw02, rw03, rw10, rw11, rw12, rw13, rw20, rw21, rw22, rw23;
    {
        const half8* pR = (const half8*)(pW + (size_t)wid * RES_WAVE);
        rw00 = pR[ 0 * 64 + lane]; rw01 = pR[ 1 * 64 + lane];
        rw02 = pR[ 2 * 64 + lane]; rw03 = pR[ 3 * 64 + lane];
        rw10 = pR[ 4 * 64 + lane]; rw11 = pR[ 5 * 64 + lane];
        rw12 = pR[ 6 * 64 + lane]; rw13 = pR[ 7 * 64 + lane];
        rw20 = pR[ 8 * 64 + lane]; rw21 = pR[ 9 * 64 + lane];
        rw22 = pR[10 * 64 + lane]; rw23 = pR[11 * 64 + lane];
    }

    // zero LDS A-buffers (pad rows 40..47 stay zero forever)
    for (int i = tid; i < 48 * SEQ_STRIDE; i += 512) sSeq[i] = (_Float16)0.f;
    for (int i = tid; i < 48 * H_STRIDE; i += 512) {
        sH0[0][i] = (_Float16)0.f; sH0[1][i] = (_Float16)0.f;
        sH1[0][i] = (_Float16)0.f; sH1[1][i] = (_Float16)0.f;
    }

    float bias0[4], bias1[4];
    #pragma unroll
    for (int g = 0; g < 4; ++g) {
        bias0[g] = bsum[g * 128 + ch];
        bias1[g] = bsum[512 + g * 128 + ch];
    }

    float c0[MT][4] = {{0}}, c1[MT][4] = {{0}};

    __syncthreads();

    // stage constant gcn columns (32..95) and seq t=0 (cols 0..31)
    for (int i = tid; i < M_BLK * (C_GCN / 2); i += 512) {
        int r = i >> 5, cp = (i & 31) * 2;
        floatx2 v = *(const floatx2*)(gcn + (size_t)(node0 + r) * C_GCN + cp);
        sSeq[r * SEQ_STRIDE + S_SEQ + cp]     = (_Float16)v.x;
        sSeq[r * SEQ_STRIDE + S_SEQ + cp + 1] = (_Float16)v.y;
    }
    {
        int r = tid >> 4, cp = (tid & 15) * 2;
        if (tid < M_BLK * 16) {
            floatx2 v = *(const floatx2*)(seq + ((size_t)(node0 + r) * T_SEQ) * S_SEQ + cp);
            sSeq[r * SEQ_STRIDE + cp]     = (_Float16)v.x;
            sSeq[r * SEQ_STRIDE + cp + 1] = (_Float16)v.y;
        }
    }
    __syncthreads();   // full drain: prologue DMAs + resident loads complete

    floatx4 acc[4][MT];
    half8 aX[MT], aY[MT];
    half8 bx0, bx1, bx2, bx3, by0, by1, by2, by3;

    const int pr = tid >> 4, pc = (tid & 15) * 2;
    const int r1 = 32 + ((tid & 127) >> 4);
    floatx2 pfa, pfb;

    // Steady-state vm queue at step top: [s0(4) s1(4) s2(4) pf(2)] = 14.
    // Per consume line: DMA next-in-ring (+4), then VMW leaves exactly the
    // 2 newer slots (+pf where older) in flight. Derived per line below.

    if (!rot) {
      // ============ canonical (waves 0-3): resident IH0 first ============
      for (int t = 0; t < T_SEQ; ++t) {
        const int cur = t & 1, nxt = cur ^ 1;
        const _Float16* h0c = &sH0[cur][0];
        _Float16*       h0n = &sH0[nxt][0];
        const _Float16* h1c = &sH1[cur][0];
        _Float16*       h1n = &sH1[nxt][0];
        {
            int tp = (t + 1 < T_SEQ) ? (t + 1) : (T_SEQ - 1);
            pfa = *(const floatx2*)(seq + ((size_t)(node0 + pr) * T_SEQ + tp) * S_SEQ + pc);
            pfb = *(const floatx2*)(seq + ((size_t)(node0 + r1) * T_SEQ + tp) * S_SEQ + pc);
        }
        // ---- phase A: resident IH0 (sSeq kt0..2) + streamed s0..s3 (HH0 x h0c) ----
        ACCINIT(bias0);
        RDA(aX, sSeq, 0, SEQ_STRIDE);
        RDA(aY, sSeq, 32, SEQ_STRIDE);  MM4(aX, rw00, rw01, rw02, rw03);
        RDA(aX, sSeq, 64, SEQ_STRIDE);  MM4(aY, rw10, rw11, rw12, rw13);
        RDA(aY, h0c, 0, H_STRIDE);      MM4(aX, rw20, rw21, rw22, rw23);
        VMW(10); RDB4(bx0, bx1, bx2, bx3, rb0);                               // B(s0); rem s1 s2 pf
        DMA(3, rb0); VMW(10); RDB4(by0, by1, by2, by3, rb1);                  // B(s1); rem s2 pf s3
                     RDA(aX, h0c, 32, H_STRIDE); MM4(aY, bx0, bx1, bx2, bx3); // s0
        DMA(4, rb1); VMW(10); RDB4(bx0, bx1, bx2, bx3, rb2);                  // B(s2); rem pf s3 s4
                     RDA(aY, h0c, 64, H_STRIDE); MM4(aX, by0, by1, by2, by3); // s1
        DMA(5, rb2); VMW(8);  RDB4(by0, by1, by2, by3, rb0);                  // B(s3); rem s4 s5
                     RDA(aX, h0c, 96, H_STRIDE); MM4(aY, bx0, bx1, bx2, bx3); // s2
        DMA(6, rb0); MM4(aX, by0, by1, by2, by3);                             // s3
        epilogue(acc, c0, h0n, quad, ch);
        BARRIER_NOVM();
        // ---- phase B: s4..7 (IH1 x h0n), s8..11 (HH1 x h1c) ----
        ACCINIT(bias1);
        VMW(8); RDB4(bx0, bx1, bx2, bx3, rb1); RDA(aY, h0n, 0, H_STRIDE);     // B(s4); rem s5 s6
        DMA(7, rb1);  VMW(8); RDB4(by0, by1, by2, by3, rb2);
                      RDA(aX, h0n, 32, H_STRIDE); MM4(aY, bx0, bx1, bx2, bx3); // s4
        DMA(8, rb2);  VMW(8); RDB4(bx0, bx1, bx2, bx3, rb0);
                      RDA(aY, h0n, 64, H_STRIDE); MM4(aX, by0, by1, by2, by3); // s5
        DMA(9, rb0);  VMW(8); RDB4(by0, by1, by2, by3, rb1);
                      RDA(aX, h0n, 96, H_STRIDE); MM4(aY, bx0, bx1, bx2, bx3); // s6
        DMA(10, rb1); VMW(8); RDB4(bx0, bx1, bx2, bx3, rb2);
                      RDA(aY, h1c, 0, H_STRIDE);  MM4(aX, by0, by1, by2, by3); // s7
        DMA(11, rb2); VMW(8); RDB4(by0, by1, by2, by3, rb0);
                      RDA(aX, h1c, 32, H_STRIDE); MM4(aY, bx0, bx1, bx2, bx3); // s8
        DMA(0, rb0);  VMW(8); RDB4(bx0, bx1, bx2, bx3, rb1);
                      RDA(aY, h1c, 64, H_STRIDE); MM4(aX, by0, by1, by2, by3); // s9
        DMA(1, rb1);  VMW(8); RDB4(by0, by1, by2, by3, rb2);
                      RDA(aX, h1c, 96, H_STRIDE); MM4(aY, bx0, bx1, bx2, bx3); // s10
        DMA(2, rb2);  MM4(aX, by0, by1, by2, by3);                             // s11
        if (t + 1 < T_SEQ) {
            sSeq[pr * SEQ_STRIDE + pc]     = (_Float16)pfa.x;
            sSeq[pr * SEQ_STRIDE + pc + 1] = (_Float16)pfa.y;
            if (tid < 128) {
                sSeq[r1 * SEQ_STRIDE + pc]     = (_Float16)pfb.x;
                sSeq[r1 * SEQ_STRIDE + pc + 1] = (_Float16)pfb.y;
            }
        }
        epilogue(acc, c1, h1n, quad, ch);
        BARRIER_NOVM();
      }
    } else {
      // ============ rotated (waves 4-7): streamed HH first ============
      // phase A: s0..s3 (HH0 x h0c) then resident IH0 (sSeq).
      // phase B: s8..11 (HH1 x h1c) then s4..7 (IH1 x h0n).
      // ring keyed by consume position: s0 rb0, s1 rb1, s2 rb2, s3 rb0,
      //   s8 rb1, s9 rb2, s10 rb0, s11 rb1, s4 rb2, s5 rb0, s6 rb1, s7 rb2.
      for (int t = 0; t < T_SEQ; ++t) {
        const int cur = t & 1, nxt = cur ^ 1;
        const _Float16* h0c = &sH0[cur][0];
        _Float16*       h0n = &sH0[nxt][0];
        const _Float16* h1c = &sH1[cur][0];
        _Float16*       h1n = &sH1[nxt][0];
        {
            int tp = (t + 1 < T_SEQ) ? (t + 1) : (T_SEQ - 1);
            pfa = *(const floatx2*)(seq + ((size_t)(node0 + pr) * T_SEQ + tp) * S_SEQ + pc);
            pfb = *(const floatx2*)(seq + ((size_t)(node0 + r1) * T_SEQ + tp) * S_SEQ + pc);
        }
        // ---- phase A rotated ----
        ACCINIT(bias0);
        RDA(aY, h0c, 0, H_STRIDE);
        VMW(10); RDB4(bx0, bx1, bx2, bx3, rb0);                               // B(s0)
        DMA(3, rb0); VMW(10); RDB4(by0, by1, by2, by3, rb1);                  // B(s1)
                     RDA(aX, h0c, 32, H_STRIDE); MM4(aY, bx0, bx1, bx2, bx3); // s0
        DMA(8, rb1); VMW(10); RDB4(bx0, bx1, bx2, bx3, rb2);                  // B(s2)
                     RDA(aY, h0c, 64, H_STRIDE); MM4(aX, by0, by1, by2, by3); // s1
        DMA(9, rb2); VMW(8);  RDB4(by0, by1, by2, by3, rb0);                  // B(s3)
                     RDA(aX, h0c, 96, H_STRIDE); MM4(aY, bx0, bx1, bx2, bx3); // s2
        DMA(10, rb0); RDA(aY, sSeq, 0, SEQ_STRIDE); MM4(aX, by0, by1, by2, by3); // s3
        RDA(aX, sSeq, 32, SEQ_STRIDE);  MM4(aY, rw00, rw01, rw02, rw03);
        RDA(aY, sSeq, 64, SEQ_STRIDE);  MM4(aX, rw10, rw11, rw12, rw13);
        MM4(aY, rw20, rw21, rw22, rw23);
        epilogue(acc, c0, h0n, quad, ch);
        BARRIER_NOVM();
        // ---- phase B rotated ----
        ACCINIT(bias1);
        VMW(8); RDB4(bx0, bx1, bx2, bx3, rb1); RDA(aY, h1c, 0, H_STRIDE);     // B(s8)
        DMA(11, rb1); VMW(8); RDB4(by0, by1, by2, by3, rb2);
                      RDA(aX, h1c, 32, H_STRIDE); MM4(aY, bx0, bx1, bx2, bx3); // s8
        DMA(4, rb2);  VMW(8); RDB4(bx0, bx1, bx2, bx3, rb0);
                      RDA(aY, h1c, 64, H_STRIDE); MM4(aX, by0, by1, by2, by3); // s9
        DMA(5, rb0);  VMW(8); RDB4(by0, by1, by2, by3, rb1);
                      RDA(aX, h1c, 96, H_STRIDE); MM4(aY, bx0, bx1, bx2, bx3); // s10
        DMA(6, rb1);  VMW(8); RDB4(bx0, bx1, bx2, bx3, rb2);
                      RDA(aY, h0n, 0, H_STRIDE);  MM4(aX, by0, by1, by2, by3); // s11
        DMA(7, rb2);  VMW(8); RDB4(by0, by1, by2, by3, rb0);
                      RDA(aX, h0n, 32, H_STRIDE); MM4(aY, bx0, bx1, bx2, bx3); // s4
        DMA(0, rb0);  VMW(8); RDB4(bx0, bx1, bx2, bx3, rb1);
                      RDA(aY, h0n, 64, H_STRIDE); MM4(aX, by0, by1, by2, by3); // s5
        DMA(1, rb1);  VMW(8); RDB4(by0, by1, by2, by3, rb2);
                      RDA(aX, h0n, 96, H_STRIDE); MM4(aY, bx0, bx1, bx2, bx3); // s6
        DMA(2, rb2);  MM4(aX, by0, by1, by2, by3);                             // s7
        if (t + 1 < T_SEQ) {
            sSeq[pr * SEQ_STRIDE + pc]     = (_Float16)pfa.x;
            sSeq[pr * SEQ_STRIDE + pc + 1] = (_Float16)pfa.y;
            if (tid < 128) {
                sSeq[r1 * SEQ_STRIDE + pc]     = (_Float16)pfb.x;
                sSeq[r1 * SEQ_STRIDE + pc + 1] = (_Float16)pfb.y;
            }
        }
        epilogue(acc, c1, h1n, quad, ch);
        BARRIER_NOVM();
      }
    }

#undef DMA

    // drain the 3 slots prefetched for the nonexistent step 96
    asm volatile("s_waitcnt vmcnt(0)" ::: "memory");

    // final h1 lives in buffer (T_SEQ & 1) == 0
    if (tid < M_BLK) {
        const _Float16* h1 = &sH1[0][tid * H_STRIDE];
        float s = fcb[0];
        #pragma unroll 16
        for (int k = 0; k < HID; ++k) s = fmaf((float)h1[k], fcw[k], s);
        out[node0 + tid] = s;
    }
}

// ---------------- launch ----------------
extern "C" void kernel_launch(void* const* d_in, const int* in_sizes, int n_in,
                              void* d_out, int out_size, void* d_ws, size_t ws_size,
                              hipStream_t stream) {
    const float* seq   = (const float*)d_in[0];
    const int*   ei    = (const int*)d_in[1];
    const float* nf    = (const float*)d_in[3];
    const float* gcn_w = (const float*)d_in[5];
    const float* gcn_b = (const float*)d_in[6];
    const float* w_ih0 = (const float*)d_in[7];
    const float* w_hh0 = (const float*)d_in[8];
    const float* b_ih0 = (const float*)d_in[9];
    const float* b_hh0 = (const float*)d_in[10];
    const float* w_ih1 = (const float*)d_in[11];
    const float* w_hh1 = (const float*)d_in[12];
    const float* b_ih1 = (const float*)d_in[13];
    const float* b_hh1 = (const float*)d_in[14];
    const float* fc_w  = (const float*)d_in[15];
    const float* fc_b  = (const float*)d_in[16];
    float* out = (float*)d_out;

    char* ws = (char*)d_ws;
    float* xw   = (float*)(ws);                    // 2,560,000 B
    float* gout = (float*)(ws + 2621440);          // 2,560,000 B
    float* deg  = (float*)(ws + 5242880);          // 40,000 B
    float* dinv = (float*)(ws + 5283840);          // 40,000 B
    float* bsum = (float*)(ws + 5324800);          // 4,096 B
    char*  pP   = (char*)(ws + 5328896);           // 491,520 B

    // GCN (fp32 exact)
    k_gcn_xw     <<<2500,  256, 0, stream>>>(nf, gcn_w, xw);
    k_deg_init   <<<40,    256, 0, stream>>>(deg);
    k_deg_count  <<<625,   256, 0, stream>>>(ei, deg);
    k_dinv       <<<40,    256, 0, stream>>>(deg, dinv);
    k_gcn_self   <<<2500,  256, 0, stream>>>(xw, dinv, gcn_b, gout);
    k_gcn_scatter<<<40000, 256, 0, stream>>>(ei, xw, dinv, gout);

    // weight prep (resident + streamed layout)
    k_pack<<<120, 256, 0, stream>>>(w_ih0, w_hh0, w_ih1, w_hh1, pP);
    k_bsum<<<4,   256, 0, stream>>>(b_ih0, b_hh0, b_ih1, b_hh1, bsum);

    // fused 2-layer LSTM + FC
    k_lstm<<<250, 512, 0, stream>>>(seq, gout, pP, bsum, fc_w, fc_b, out);
}